// Round 12
// baseline (337.707 us; speedup 1.0000x reference)
//
#include <hip/hip_runtime.h>
#include <hip/hip_bf16.h>

#define BATCH 8192
#define DIM   1024
#define INV_TAU (1.0f / 0.07f)
#define TOPM 0.95f
#define BOTM 0.05f

#define BM 256
#define BN 256
#define BK 128          // fp8: 128 k-bytes per K-tile (same 128B LDS rows as bf16-BK64)
#define NT (DIM / BK)   // 8 K-tiles per output tile

typedef __attribute__((ext_vector_type(8)))  int   v8i;
typedef __attribute__((ext_vector_type(16))) float f32x16;

typedef __attribute__((address_space(3))) void       lds_void_t;
typedef const __attribute__((address_space(1))) void gbl_void_t;

__device__ inline void async_copy16(const void* g, void* l) {
    __builtin_amdgcn_global_load_lds((gbl_void_t*)g, (lds_void_t*)l, 16, 0, 0);
}

// ---------------------------------------------------------------------------
// Kernel 1: per-row L2 norms, EXACT fp32 pos (diag similarity), fp8-e4m3
// normalized writes (4B/thread), zero-init S.
// ---------------------------------------------------------------------------
__global__ __launch_bounds__(256) void prep_kernel(
    const float* __restrict__ A, const float* __restrict__ B,
    unsigned char* __restrict__ An, unsigned char* __restrict__ Bn,
    float* __restrict__ pos, float* __restrict__ S)
{
    int row = blockIdx.x;
    int t = threadIdx.x;
    const float4* a4 = (const float4*)(A + (size_t)row * DIM);
    const float4* b4 = (const float4*)(B + (size_t)row * DIM);
    float4 av = a4[t];
    float4 bv = b4[t];
    float sa = av.x*av.x + av.y*av.y + av.z*av.z + av.w*av.w;
    float sb = bv.x*bv.x + bv.y*bv.y + bv.z*bv.z + bv.w*bv.w;
    float dp = av.x*bv.x + av.y*bv.y + av.z*bv.z + av.w*bv.w;
    #pragma unroll
    for (int d = 32; d > 0; d >>= 1) {
        sa += __shfl_down(sa, d);
        sb += __shfl_down(sb, d);
        dp += __shfl_down(dp, d);
    }
    __shared__ float red[3][4];
    int lane = t & 63, w = t >> 6;
    if (lane == 0) { red[0][w] = sa; red[1][w] = sb; red[2][w] = dp; }
    __syncthreads();
    sa = red[0][0] + red[0][1] + red[0][2] + red[0][3];
    sb = red[1][0] + red[1][1] + red[1][2] + red[1][3];
    dp = red[2][0] + red[2][1] + red[2][2] + red[2][3];
    float ra = rsqrtf(sa);
    float rb = rsqrtf(sb);
    if (t == 0) {
        pos[row] = dp * ra * rb;
        S[row] = 0.0f;
    }
    int ua = 0, ub = 0;
    ua = __builtin_amdgcn_cvt_pk_fp8_f32(av.x * ra, av.y * ra, ua, false);
    ua = __builtin_amdgcn_cvt_pk_fp8_f32(av.z * ra, av.w * ra, ua, true);
    ub = __builtin_amdgcn_cvt_pk_fp8_f32(bv.x * rb, bv.y * rb, ub, false);
    ub = __builtin_amdgcn_cvt_pk_fp8_f32(bv.z * rb, bv.w * rb, ub, true);
    ((int*)(An + (size_t)row * DIM))[t] = ua;
    ((int*)(Bn + (size_t)row * DIM))[t] = ub;
}

// ---------------------------------------------------------------------------
// Kernel 2: PERSISTENT 256x256 fp8 MX-MFMA GEMM + fused masked exp-sum.
// Same skeleton/swizzle/ledger as the (passing) bf16 R11 kernel; dtype fp8
// e4m3 with unit scales via mfma_scale_f32_32x32x64_f8f6f4 (fmt 0/0).
// K-tile = 128 k-bytes -> LDS rows stay 128B, swizzle identical; per-FLOP
// LDS traffic and HBM fetch halve; 8 K-tiles per output tile.
//
// Per K-tile t (p=t&1; read A[p],B[p]):
//  phX: BAR;SCH; ds aF(ks0)(8 b128), bF(ks0+ks1)(8); stage A(t+1)h0+h1 ->
//       A[p^1]; 8 MFMA ks0; LGKM0
//  phY: BAR;SCH; ds aF(ks1)(8); stage B(t+2)h0+h1 -> B[p];
//       8 MFMA ks1; LGKM0; VMC(4)
// vmcnt ledger at VMC(4): [B(t+1)4][A(t+1)4][B(t+2)4]=12 -> drains
//  B(t+1)+A(t+1), leaves B(t+2).  WAR: stage B[p]@phY after phX LGKM0+BAR
//  retired all b-reads of B[p]; stage A[p^1]@phX after prev phY LGKM0+BAR.
// Epilogue: 32x32 C/D map col=lane&31, row=(r&3)+8*(r>>2)+4*(lane>>5);
// per-wave 32-lane-half shuffle reduce -> LDS rowAcc (256 f32) -> one
// global atomic per row per block-tile (same atomic count as bf16 rounds).
// ---------------------------------------------------------------------------
__global__ __launch_bounds__(512, 1) void sim_loss_kernel(
    const unsigned char* __restrict__ An, const unsigned char* __restrict__ Bn,
    const float* __restrict__ pos, float* __restrict__ S)
{
    __shared__ char lds[132096];   // A[2]:0,32768  B[2]:65536,98304  rowAcc:131072
    float* rowAcc = (float*)(lds + 131072);

    int tid  = threadIdx.x;
    int lane = tid & 63;
    int wave = tid >> 6;
    int wm = wave >> 2, wn = wave & 3;   // 2x4 wave grid, 128x64 per wave
    int l31 = lane & 31;
    int hi  = lane >> 5;

    int bid = blockIdx.x;   // 0..255

#define BASES(g, rB, cB) do {                                                        \
    int xcd_ = bid & 7, jj_ = bid >> 3;                                              \
    int qr_ = (g) >> 1, qc_ = ((g) & 1) ^ (qr_ & 1);                                 \
    (rB) = (qr_ * 16 + (xcd_ >> 1) * 4 + (jj_ >> 3)) * BM;                           \
    (cB) = (qc_ * 16 + (xcd_ & 1) * 8 + (jj_ & 7)) * BN;                             \
} while (0)

    f32x16 acc[4][2] = {};   // [mt][nt], 32x32 tiles -> 128 VGPR
    v8i aF[4];               // A frags of current k-step (4 m-tiles)
    v8i bF[2][2];            // B frags [nt][ks] (both k-steps, read in phX)

    // ds_read addressing (read-side swizzle; row&7 == lane&7 for all frags)
    int sw = (lane & 7) << 4;
    int cc00 = (hi * 32) ^ sw;
    int cc01 = (hi * 32 + 16) ^ sw;
    int cc10 = (64 + hi * 32) ^ sw;
    int cc11 = (64 + hi * 32 + 16) ^ sw;
    int aRow = (wm * 128 + l31) * 128;
    int bRow = (wn * 64 + l31) * 128;

    // staging addressing (source-side swizzle, linear LDS dest) — byte-
    // identical to the bf16 version (128B k-slots, 128B LDS rows).
    int strow = tid >> 3;                                  // 0..63
    int scb   = ((tid & 7) * 16) ^ ((strow & 7) << 4);
    int ldst = tid * 16;

#define PANELS(rB, cB, pA, pB) do {                                                  \
    (pA) = (const char*)An + (size_t)((rB) + strow) * 1024 + scb;                    \
    (pB) = (const char*)Bn + (size_t)((cB) + strow) * 1024 + scb;                    \
} while (0)

#define STAGE(gbase, u, h, ldsdst) do {                                              \
    async_copy16((gbase) + (size_t)(h) * 131072 + (size_t)(u) * 128,                 \
                 (ldsdst) + (h) * 16384 + ldst);                                     \
    async_copy16((gbase) + (size_t)(h) * 131072 + 65536 + (size_t)(u) * 128,         \
                 (ldsdst) + (h) * 16384 + 8192 + ldst);                              \
} while (0)

#define PACK8(d0, d1) (v8i){d0.x, d0.y, d0.z, d0.w, d1.x, d1.y, d1.z, d1.w}

#define LDA_(p, c_a, c_b) do {                                                       \
    const char* _s = lds + (p) * 32768;                                              \
    _Pragma("unroll") for (int mt = 0; mt < 4; ++mt) {                               \
        int4 d0 = *(const int4*)(_s + aRow + mt * 4096 + (c_a));                     \
        int4 d1 = *(const int4*)(_s + aRow + mt * 4096 + (c_b));                     \
        aF[mt] = PACK8(d0, d1);                                                      \
    }                                                                                \
} while (0)

#define LDBB_(p) do {                                                                \
    const char* _s = lds + 65536 + (p) * 32768;                                      \
    _Pragma("unroll") for (int nt = 0; nt < 2; ++nt) {                               \
        int4 e0 = *(const int4*)(_s + bRow + nt * 4096 + cc00);                      \
        int4 e1 = *(const int4*)(_s + bRow + nt * 4096 + cc01);                      \
        bF[nt][0] = PACK8(e0, e1);                                                   \
        int4 e2 = *(const int4*)(_s + bRow + nt * 4096 + cc10);                      \
        int4 e3 = *(const int4*)(_s + bRow + nt * 4096 + cc11);                      \
        bF[nt][1] = PACK8(e2, e3);                                                   \
    }                                                                                \
} while (0)

// 8 MFMA for one k-step: fmtA=0 (fp8), fmtB=0, unit scales (E8M0 127 = 2^0)
#define MMK_(ks) do {                                                                \
    _Pragma("unroll") for (int mt = 0; mt < 4; ++mt)                                 \
    _Pragma("unroll") for (int nt = 0; nt < 2; ++nt)                                 \
        acc[mt][nt] = __builtin_amdgcn_mfma_scale_f32_32x32x64_f8f6f4(               \
            aF[mt], bF[nt][ks], acc[mt][nt], 0, 0,                                   \
            0, 0x7F7F7F7F, 0, 0x7F7F7F7F);                                           \
} while (0)

#define BAR() __builtin_amdgcn_s_barrier()
#define SCH() __builtin_amdgcn_sched_barrier(0)
#define LGKM0() asm volatile("s_waitcnt lgkmcnt(0)" ::: "memory")
#define VMC(n)  asm volatile("s_waitcnt vmcnt(" #n ")" ::: "memory")
#define PRI1() __builtin_amdgcn_s_setprio(1)
#define PRI0() __builtin_amdgcn_s_setprio(0)

#define KTILE(p, pA_, uA, pB_, uB) do {                                              \
    char* stA = lds + ((p) ^ 1) * 32768;                                             \
    char* stB = lds + 65536 + (p) * 32768;                                           \
    /* phX: k-step 0 */                                                              \
    BAR(); SCH();                                                                    \
    LDA_((p), cc00, cc01); LDBB_((p));                                               \
    STAGE((pA_), (uA), 0, stA); STAGE((pA_), (uA), 1, stA);                          \
    PRI1(); MMK_(0); PRI0();                                                         \
    LGKM0();                                                                         \
    /* phY: k-step 1 */                                                              \
    BAR(); SCH();                                                                    \
    LDA_((p), cc10, cc11);                                                           \
    STAGE((pB_), (uB), 0, stB); STAGE((pB_), (uB), 1, stB);                          \
    PRI1(); MMK_(1); PRI0();                                                         \
    LGKM0(); VMC(4);                                                                 \
} while (0)

    int rowB, colB;
    BASES(0, rowB, colB);
    const char *gAc, *gBc;
    PANELS(rowB, colB, gAc, gBc);

    // Prologue: A(0)->A[0], B(0)->B[0], B(1)->B[1]; drain to 4 (keep B(1)).
    STAGE(gAc, 0, 0, lds);
    STAGE(gAc, 0, 1, lds);
    STAGE(gBc, 0, 0, lds + 65536);
    STAGE(gBc, 0, 1, lds + 65536);
    STAGE(gBc, 1, 0, lds + 98304);
    STAGE(gBc, 1, 1, lds + 98304);
    VMC(4);

    #pragma unroll 1
    for (int g = 0; g < 4; ++g) {
        int gn = (g < 3) ? g + 1 : 3;
        int rowBn, colBn;
        BASES(gn, rowBn, colBn);
        const char *gAn2, *gBn2;
        PANELS(rowBn, colBn, gAn2, gBn2);

        #pragma unroll 1
        for (int tt = 0; tt < 3; ++tt) {
            KTILE(0, gAc, 2 * tt + 1, gBc, 2 * tt + 2);
            KTILE(1, gAc, 2 * tt + 2, gBc, 2 * tt + 3);
        }
        // t=6: A(7); B wraps to next tile's B(0).  t=7: wrap A(0)/B(1).
        KTILE(0, gAc, 7, gBn2, 0);
        KTILE(1, gAn2, 0, gBn2, 1);

        // ---- Epilogue for tile g (next tile's operands already in flight) ----
        BAR();
        if (tid < 256) rowAcc[tid] = 0.0f;
        BAR();
        #pragma unroll
        for (int mt = 0; mt < 4; ++mt) {
            #pragma unroll
            for (int r = 0; r < 16; ++r) {
                int io = wm * 128 + mt * 32 + (r & 3) + 8 * (r >> 2) + 4 * hi;
                int i  = rowB + io;
                float p  = pos[i];
                float up = TOPM * p, lo = BOTM * p;
                float rs = 0.0f;
                #pragma unroll
                for (int nt = 0; nt < 2; ++nt) {
                    float sv = acc[mt][nt][r];
                    int col = colB + wn * 64 + nt * 32 + l31;
                    if (sv <= up && sv >= lo && col != i)
                        rs += __expf((sv - p) * INV_TAU);
                }
                #pragma unroll
                for (int d = 1; d < 32; d <<= 1)
                    rs += __shfl_xor(rs, d);
                if (l31 == 0 && rs != 0.0f)
                    atomicAdd(&rowAcc[io], rs);
            }
        }
        LGKM0();
        BAR();
        if (tid < 256) {
            float v = rowAcc[tid];
            if (v > 0.0f) atomicAdd(&S[rowB + tid], v);
        }
        #pragma unroll
        for (int m2 = 0; m2 < 4; ++m2)
            #pragma unroll
            for (int n2 = 0; n2 < 2; ++n2)
                acc[m2][n2] = (f32x16)(0.0f);

        gAc = gAn2; gBc = gBn2; rowB = rowBn; colB = colBn;
    }
    LGKM0();
    VMC(0);    // drain redundant g=3 staging + atomics before endpgm

#undef BASES
#undef PANELS
#undef STAGE
#undef PACK8
#undef LDA_
#undef LDBB_
#undef MMK_
#undef BAR
#undef SCH
#undef LGKM0
#undef VMC
#undef PRI1
#undef PRI0
#undef KTILE
}

// ---------------------------------------------------------------------------
// Kernel 3: per_row = log1p(S_i) for rows with any negative; mean over valid.
// ---------------------------------------------------------------------------
__global__ __launch_bounds__(256) void finalize_kernel(
    const float* __restrict__ S, float* __restrict__ out)
{
    int t = threadIdx.x;
    float tot = 0.0f;
    int c = 0;
    for (int i = t; i < BATCH; i += 256) {
        float s = S[i];
        if (s > 0.0f) { tot += log1pf(s); c += 1; }
    }
    #pragma unroll
    for (int d = 32; d > 0; d >>= 1) {
        tot += __shfl_down(tot, d);
        c   += __shfl_down(c, d);
    }
    __shared__ float st[4];
    __shared__ int   sc[4];
    int lane = t & 63, w = t >> 6;
    if (lane == 0) { st[w] = tot; sc[w] = c; }
    __syncthreads();
    if (t == 0) {
        float T = st[0] + st[1] + st[2] + st[3];
        int   C = sc[0] + sc[1] + sc[2] + sc[3];
        out[0] = T / (float)(C > 0 ? C : 1);
    }
}

extern "C" void kernel_launch(void* const* d_in, const int* in_sizes, int n_in,
                              void* d_out, int out_size, void* d_ws, size_t ws_size,
                              hipStream_t stream) {
    const float* A = (const float*)d_in[0];
    const float* B = (const float*)d_in[1];

    char* ws = (char*)d_ws;
    unsigned char* An = (unsigned char*)ws;
    unsigned char* Bn = An + (size_t)BATCH * DIM;
    float* pos = (float*)(Bn + (size_t)BATCH * DIM);
    float* S   = pos + BATCH;
    float* out = (float*)d_out;

    prep_kernel<<<BATCH, 256, 0, stream>>>(A, B, An, Bn, pos, S);
    sim_loss_kernel<<<256, 512, 0, stream>>>(An, Bn, pos, S);
    finalize_kernel<<<1, 256, 0, stream>>>(S, out);
}

// Round 13
// 222.100 us; speedup vs baseline: 1.5205x; 1.5205x over previous
//
#include <hip/hip_runtime.h>
#include <hip/hip_bf16.h>

#define BATCH 8192
#define DIM   1024
#define INV_TAU (1.0f / 0.07f)
#define TOPM 0.95f
#define BOTM 0.05f

#define BM 256
#define BN 256
#define BK 64
#define NT (DIM / BK)   // 16 K-tiles per output tile

typedef __attribute__((ext_vector_type(4))) float f32x4;
typedef __attribute__((ext_vector_type(8))) short bf16x8;

typedef __attribute__((address_space(3))) void       lds_void_t;
typedef const __attribute__((address_space(1))) void gbl_void_t;

__device__ inline void async_copy16(const void* g, void* l) {
    __builtin_amdgcn_global_load_lds((gbl_void_t*)g, (lds_void_t*)l, 16, 0, 0);
}

__device__ inline unsigned short f2bf(float f) {
    __hip_bfloat16 h = __float2bfloat16(f);
    return *reinterpret_cast<unsigned short*>(&h);
}

// ---------------------------------------------------------------------------
// Kernel 1: per-row L2 norms, exact fp32 pos, bf16 writes, zero-init S.
// ---------------------------------------------------------------------------
__global__ __launch_bounds__(256) void prep_kernel(
    const float* __restrict__ A, const float* __restrict__ B,
    unsigned short* __restrict__ An, unsigned short* __restrict__ Bn,
    float* __restrict__ pos, float* __restrict__ S)
{
    int row = blockIdx.x;
    int t = threadIdx.x;
    const float4* a4 = (const float4*)(A + (size_t)row * DIM);
    const float4* b4 = (const float4*)(B + (size_t)row * DIM);
    float4 av = a4[t];
    float4 bv = b4[t];
    float sa = av.x*av.x + av.y*av.y + av.z*av.z + av.w*av.w;
    float sb = bv.x*bv.x + bv.y*bv.y + bv.z*bv.z + bv.w*bv.w;
    float dp = av.x*bv.x + av.y*bv.y + av.z*bv.z + av.w*bv.w;
    #pragma unroll
    for (int d = 32; d > 0; d >>= 1) {
        sa += __shfl_down(sa, d);
        sb += __shfl_down(sb, d);
        dp += __shfl_down(dp, d);
    }
    __shared__ float red[3][4];
    int lane = t & 63, w = t >> 6;
    if (lane == 0) { red[0][w] = sa; red[1][w] = sb; red[2][w] = dp; }
    __syncthreads();
    sa = red[0][0] + red[0][1] + red[0][2] + red[0][3];
    sb = red[1][0] + red[1][1] + red[1][2] + red[1][3];
    dp = red[2][0] + red[2][1] + red[2][2] + red[2][3];
    float ra = rsqrtf(sa);
    float rb = rsqrtf(sb);
    if (t == 0) {
        pos[row] = dp * ra * rb;
        S[row] = 0.0f;
    }
    ushort4 oa, ob;
    oa.x = f2bf(av.x * ra); oa.y = f2bf(av.y * ra);
    oa.z = f2bf(av.z * ra); oa.w = f2bf(av.w * ra);
    ob.x = f2bf(bv.x * rb); ob.y = f2bf(bv.y * rb);
    ob.z = f2bf(bv.z * rb); ob.w = f2bf(bv.w * rb);
    ((ushort4*)(An + (size_t)row * DIM))[t] = oa;
    ((ushort4*)(Bn + (size_t)row * DIM))[t] = ob;
}

// ---------------------------------------------------------------------------
// Kernel 2: PERSISTENT 256x256 MFMA GEMM + fused masked exp-sum.
// m201-style 8-phase-per-2-K-tiles schedule with BOTH enablers combined:
//  (a) barrier-first-then-lgkmcnt(0) phase body (waves overlap LDS drain
//      with other waves' MFMA), and
//  (b) staging ledger with REAL issue-to-gate lead: 1 half-tile staged per
//      phase, single counted VMC(2) at P4; no half is gated in its own
//      issue phase (R6 gated A h1 at 0-phase lead = de-facto drain-0).
//
// Per K-tile s (p=s&1; quadrant order 00,01,11,10; 16 MFMA each):
//  P1: ds a0(8),b0(4); stage A(s+1)h1->A[p^1]; lgkm(8); BAR; lgkm0;
//      MM(mh0,nh0); BAR
//  P2: ds b1(4);       stage B(s+1)h0->B[p^1];          BAR; lgkm0;
//      MM(mh0,nh1); BAR
//  P3: ds a1(8);       stage B(s+1)h1->B[p^1];          BAR; lgkm0;
//      MM(mh1,nh1); BAR
//  P4: (no ds);        stage A(s+2)h0->A[p];            BAR;
//      MM(mh1,nh0); VMC(2); BAR
// vmcnt ledger at VMC(2)@P4(s): outstanding (2 loads each)
//  [A(s+1)h1 @P1][B(s+1)h0 @P2][B(s+1)h1 @P3][A(s+2)h0 @P4] = 8
//  -> drains A(s+1)+B(s+1) completely, leaves A(s+2)h0.  Leads: A(s)h0
//  issued P4(s-2) gated P4(s-1) = 4 phases; A h1 3; B h0 2; B h1 1.
// WAR: A[p^1]h1 stage@P1(s): last read P3(s-1) a1, drained by its lgkm0
//  before MFMA, 2 barriers before.  B[p^1] stages@P2/P3: last read P2(s-1).
//  A[p]h0 stage@P4(s): rows 64-127 read P3(s) a1, drained at P3 lgkm0,
//  barrier between.  Epilogue vmem is older than following stages; later
//  VMC(2) over-drains it (safe).
// ---------------------------------------------------------------------------
__global__ __launch_bounds__(512, 1) void sim_loss_kernel(
    const unsigned short* __restrict__ An, const unsigned short* __restrict__ Bn,
    const float* __restrict__ pos, float* __restrict__ S)
{
    __shared__ char lds[131072];   // A[2]: 0,32768 ; B[2]: 65536, 98304

    int tid  = threadIdx.x;
    int lane = tid & 63;
    int wave = tid >> 6;
    int wm = wave >> 2, wn = wave & 3;   // 2x4 wave grid, 128x64 per wave
    int fr = lane & 15;
    int q  = lane >> 4;

    int bid = blockIdx.x;   // 0..255

#define BASES(g, rB, cB) do {                                                        \
    int xcd_ = bid & 7, jj_ = bid >> 3;                                              \
    int qr_ = (g) >> 1, qc_ = ((g) & 1) ^ (qr_ & 1);                                 \
    (rB) = (qr_ * 16 + (xcd_ >> 1) * 4 + (jj_ >> 3)) * BM;                           \
    (cB) = (qc_ * 16 + (xcd_ & 1) * 8 + (jj_ & 7)) * BN;                             \
} while (0)

    f32x4 acc[8][4] = {};
    bf16x8 a[4][2];      // current mh half: 4 m-frags x 2 k-slices
    bf16x8 b0[2][2];     // nh0 fragments (read P1, used P1/P4)
    bf16x8 b1[2][2];     // nh1 fragments (read P2, used P2/P3)

    // ds_read addressing (read-side swizzle)
    int sw = (fr & 7) << 4;
    int c0 = (q * 16) ^ sw;
    int c1 = (64 + q * 16) ^ sw;
    int aRow = (wm * 128 + fr) * 128;
    int bRow = (wn * 64 + fr) * 128;

    // staging addressing (source-side swizzle, linear LDS dest)
    int strow = tid >> 3;                                  // 0..63
    int scb   = ((tid & 7) * 16) ^ ((strow & 7) << 4);
    int ldst = tid * 16;

#define PANELS(rB, cB, pA, pB) do {                                                  \
    (pA) = (const char*)An + (size_t)((rB) + strow) * 2048 + scb;                    \
    (pB) = (const char*)Bn + (size_t)((cB) + strow) * 2048 + scb;                    \
} while (0)

#define STAGE(gbase, u, h, ldsdst) do {                                              \
    async_copy16((gbase) + (size_t)(h) * 262144 + (size_t)(u) * 128,                 \
                 (ldsdst) + (h) * 16384 + ldst);                                     \
    async_copy16((gbase) + (size_t)(h) * 262144 + 131072 + (size_t)(u) * 128,        \
                 (ldsdst) + (h) * 16384 + 8192 + ldst);                              \
} while (0)

#define LDA_(p, mh) do {                                                             \
    const char* _s = lds + (p) * 32768;                                              \
    _Pragma("unroll") for (int m = 0; m < 4; ++m) {                                  \
        a[m][0] = *(const bf16x8*)(_s + aRow + (mh) * 8192 + m * 2048 + c0);         \
        a[m][1] = *(const bf16x8*)(_s + aRow + (mh) * 8192 + m * 2048 + c1);         \
    }                                                                                \
} while (0)

#define LDB_(arr, p, nh) do {                                                        \
    const char* _s = lds + 65536 + (p) * 32768;                                      \
    _Pragma("unroll") for (int n = 0; n < 2; ++n) {                                  \
        arr[n][0] = *(const bf16x8*)(_s + bRow + (nh) * 4096 + n * 2048 + c0);       \
        arr[n][1] = *(const bf16x8*)(_s + bRow + (nh) * 4096 + n * 2048 + c1);       \
    }                                                                                \
} while (0)

#define MM_(barr, mo, no) do {                                                       \
    _Pragma("unroll") for (int m = 0; m < 4; ++m)                                    \
    _Pragma("unroll") for (int n = 0; n < 2; ++n) {                                  \
        acc[(mo)+m][(no)+n] = __builtin_amdgcn_mfma_f32_16x16x32_bf16(               \
            a[m][0], barr[n][0], acc[(mo)+m][(no)+n], 0, 0, 0);                      \
        acc[(mo)+m][(no)+n] = __builtin_amdgcn_mfma_f32_16x16x32_bf16(               \
            a[m][1], barr[n][1], acc[(mo)+m][(no)+n], 0, 0, 0);                      \
    }                                                                                \
} while (0)

#define BAR() __builtin_amdgcn_s_barrier()
#define SCH() __builtin_amdgcn_sched_barrier(0)
#define LGKM(n) asm volatile("s_waitcnt lgkmcnt(" #n ")" ::: "memory")
#define VMC(n)  asm volatile("s_waitcnt vmcnt(" #n ")" ::: "memory")
#define PRI1() __builtin_amdgcn_s_setprio(1)
#define PRI0() __builtin_amdgcn_s_setprio(0)

// gA1/uA1: A(s+1) panel+slot; gB1/uB1: B(s+1); gA2/uA2: A(s+2)
#define KTILE(p, gA1, uA1, gB1, uB1, gA2, uA2) do {                                  \
    char* stA1 = lds + ((p) ^ 1) * 32768;                                            \
    char* stB1 = lds + 65536 + ((p) ^ 1) * 32768;                                    \
    char* stA2 = lds + (p) * 32768;                                                  \
    /* P1: quad (mh0,nh0) */                                                         \
    LDA_((p), 0); LDB_(b0, (p), 0); STAGE((gA1), (uA1), 1, stA1);                    \
    LGKM(8); BAR(); SCH();                                                           \
    LGKM(0); PRI1(); MM_(b0, 0, 0); PRI0(); BAR(); SCH();                            \
    /* P2: quad (mh0,nh1) */                                                         \
    LDB_(b1, (p), 1); STAGE((gB1), (uB1), 0, stB1);                                  \
    BAR(); SCH();                                                                    \
    LGKM(0); PRI1(); MM_(b1, 0, 2); PRI0(); BAR(); SCH();                            \
    /* P3: quad (mh1,nh1) */                                                         \
    LDA_((p), 1); STAGE((gB1), (uB1), 1, stB1);                                      \
    BAR(); SCH();                                                                    \
    LGKM(0); PRI1(); MM_(b1, 4, 2); PRI0(); BAR(); SCH();                            \
    /* P4: quad (mh1,nh0) */                                                         \
    STAGE((gA2), (uA2), 0, stA2);                                                    \
    BAR(); SCH();                                                                    \
    PRI1(); MM_(b0, 4, 0); PRI0(); VMC(2); BAR(); SCH();                             \
} while (0)

    int rowB, colB;
    BASES(0, rowB, colB);
    const char *gAc, *gBc;
    PANELS(rowB, colB, gAc, gBc);

    // Prologue: A(0)h0,h1 -> A[0]; B(0)h0,h1 -> B[0]; A(1)h0 -> A[1];
    // drain A(0)+B(0) (vmcnt 2 leaves A(1)h0 in flight).
    STAGE(gAc, 0, 0, lds);
    STAGE(gAc, 0, 1, lds);
    STAGE(gBc, 0, 0, lds + 65536);
    STAGE(gBc, 0, 1, lds + 65536);
    STAGE(gAc, 1, 0, lds + 32768);
    VMC(2);
    BAR();
    SCH();

    #pragma unroll 1
    for (int g = 0; g < 4; ++g) {
        int gn = (g < 3) ? g + 1 : 3;
        int rowBn, colBn;
        BASES(gn, rowBn, colBn);
        const char *gAn2, *gBn2;
        PANELS(rowBn, colBn, gAn2, gBn2);

        // t = 0..13: all staging references stay inside gen g.
        #pragma unroll 1
        for (int tt = 0; tt < 7; ++tt) {
            int t0 = 2 * tt;
            KTILE(0, gAc, t0 + 1, gBc, t0 + 1, gAc, t0 + 2);
            KTILE(1, gAc, t0 + 2, gBc, t0 + 2, gAc, t0 + 3);
        }
        // t=14: A(15),B(15) in-gen; A(16) -> next gen slot 0.
        KTILE(0, gAc, 15, gBc, 15, gAn2, 0);
        // t=15: A(16),B(16) -> next gen slot 0; A(17) -> next gen slot 1.
        KTILE(1, gAn2, 0, gBn2, 0, gAn2, 1);

        // Epilogue for tile g (next gen's operands staged/drained already).
        #pragma unroll
        for (int m = 0; m < 8; ++m) {
            #pragma unroll
            for (int j2 = 0; j2 < 4; ++j2) {
                int i = rowB + wm * 128 + m * 16 + q * 4 + j2;
                float p  = pos[i];
                float up = TOPM * p, lo = BOTM * p;
                float rs = 0.0f;
                #pragma unroll
                for (int n = 0; n < 4; ++n) {
                    float sv = acc[m][n][j2];
                    int col = colB + wn * 64 + n * 16 + fr;
                    if (sv <= up && sv >= lo && col != i)
                        rs += __expf((sv - p) * INV_TAU);
                }
                #pragma unroll
                for (int d = 1; d < 16; d <<= 1)
                    rs += __shfl_xor(rs, d);
                if (fr == 0 && rs != 0.0f)
                    atomicAdd(&S[i], rs);
            }
        }
        #pragma unroll
        for (int m2 = 0; m2 < 8; ++m2)
            #pragma unroll
            for (int n2 = 0; n2 < 4; ++n2)
                acc[m2][n2] = (f32x4){0.0f, 0.0f, 0.0f, 0.0f};

        gAc = gAn2; gBc = gBn2; rowB = rowBn; colB = colBn;
    }
    LGKM(0);
    VMC(0);    // drain redundant g=3 restages + atomics before endpgm

#undef BASES
#undef PANELS
#undef STAGE
#undef LDA_
#undef LDB_
#undef MM_
#undef BAR
#undef SCH
#undef LGKM
#undef VMC
#undef PRI1
#undef PRI0
#undef KTILE
}

// ---------------------------------------------------------------------------
// Kernel 3: per_row = log1p(S_i) for rows with any negative; mean over valid.
// ---------------------------------------------------------------------------
__global__ __launch_bounds__(256) void finalize_kernel(
    const float* __restrict__ S, float* __restrict__ out)
{
    int t = threadIdx.x;
    float tot = 0.0f;
    int c = 0;
    for (int i = t; i < BATCH; i += 256) {
        float s = S[i];
        if (s > 0.0f) { tot += log1pf(s); c += 1; }
    }
    #pragma unroll
    for (int d = 32; d > 0; d >>= 1) {
        tot += __shfl_down(tot, d);
        c   += __shfl_down(c, d);
    }
    __shared__ float st[4];
    __shared__ int   sc[4];
    int lane = t & 63, w = t >> 6;
    if (lane == 0) { st[w] = tot; sc[w] = c; }
    __syncthreads();
    if (t == 0) {
        float T = st[0] + st[1] + st[2] + st[3];
        int   C = sc[0] + sc[1] + sc[2] + sc[3];
        out[0] = T / (float)(C > 0 ? C : 1);
    }
}

extern "C" void kernel_launch(void* const* d_in, const int* in_sizes, int n_in,
                              void* d_out, int out_size, void* d_ws, size_t ws_size,
                              hipStream_t stream) {
    const float* A = (const float*)d_in[0];
    const float* B = (const float*)d_in[1];

    char* ws = (char*)d_ws;
    unsigned short* An = (unsigned short*)ws;
    unsigned short* Bn = An + (size_t)BATCH * DIM;
    float* pos = (float*)(Bn + (size_t)BATCH * DIM);
    float* S   = pos + BATCH;
    float* out = (float*)d_out;

    prep_kernel<<<BATCH, 256, 0, stream>>>(A, B, An, Bn, pos, S);
    sim_loss_kernel<<<256, 512, 0, stream>>>(An, Bn, pos, S);
    finalize_kernel<<<1, 256, 0, stream>>>(S, out);
}

// Round 14
// 221.483 us; speedup vs baseline: 1.5247x; 1.0028x over previous
//
#include <hip/hip_runtime.h>
#include <hip/hip_bf16.h>

#define BATCH 8192
#define DIM   1024
#define INV_TAU (1.0f / 0.07f)
#define TOPM 0.95f
#define BOTM 0.05f

#define BM 256
#define BN 256
#define BK 64
#define NT (DIM / BK)   // 16 K-tiles per output tile

typedef __attribute__((ext_vector_type(4))) float f32x4;
typedef __attribute__((ext_vector_type(8))) short bf16x8;

typedef __attribute__((address_space(3))) void       lds_void_t;
typedef const __attribute__((address_space(1))) void gbl_void_t;

__device__ inline void async_copy16(const void* g, void* l) {
    __builtin_amdgcn_global_load_lds((gbl_void_t*)g, (lds_void_t*)l, 16, 0, 0);
}

__device__ inline unsigned short f2bf(float f) {
    __hip_bfloat16 h = __float2bfloat16(f);
    return *reinterpret_cast<unsigned short*>(&h);
}

// ---------------------------------------------------------------------------
// Kernel 1: per-row L2 norms, exact fp32 pos, bf16 writes, zero-init S.
// ---------------------------------------------------------------------------
__global__ __launch_bounds__(256) void prep_kernel(
    const float* __restrict__ A, const float* __restrict__ B,
    unsigned short* __restrict__ An, unsigned short* __restrict__ Bn,
    float* __restrict__ pos, float* __restrict__ S)
{
    int row = blockIdx.x;
    int t = threadIdx.x;
    const float4* a4 = (const float4*)(A + (size_t)row * DIM);
    const float4* b4 = (const float4*)(B + (size_t)row * DIM);
    float4 av = a4[t];
    float4 bv = b4[t];
    float sa = av.x*av.x + av.y*av.y + av.z*av.z + av.w*av.w;
    float sb = bv.x*bv.x + bv.y*bv.y + bv.z*bv.z + bv.w*bv.w;
    float dp = av.x*bv.x + av.y*bv.y + av.z*bv.z + av.w*bv.w;
    #pragma unroll
    for (int d = 32; d > 0; d >>= 1) {
        sa += __shfl_down(sa, d);
        sb += __shfl_down(sb, d);
        dp += __shfl_down(dp, d);
    }
    __shared__ float red[3][4];
    int lane = t & 63, w = t >> 6;
    if (lane == 0) { red[0][w] = sa; red[1][w] = sb; red[2][w] = dp; }
    __syncthreads();
    sa = red[0][0] + red[0][1] + red[0][2] + red[0][3];
    sb = red[1][0] + red[1][1] + red[1][2] + red[1][3];
    dp = red[2][0] + red[2][1] + red[2][2] + red[2][3];
    float ra = rsqrtf(sa);
    float rb = rsqrtf(sb);
    if (t == 0) {
        pos[row] = dp * ra * rb;
        S[row] = 0.0f;
    }
    ushort4 oa, ob;
    oa.x = f2bf(av.x * ra); oa.y = f2bf(av.y * ra);
    oa.z = f2bf(av.z * ra); oa.w = f2bf(av.w * ra);
    ob.x = f2bf(bv.x * rb); ob.y = f2bf(bv.y * rb);
    ob.z = f2bf(bv.z * rb); ob.w = f2bf(bv.w * rb);
    ((ushort4*)(An + (size_t)row * DIM))[t] = oa;
    ((ushort4*)(Bn + (size_t)row * DIM))[t] = ob;
}

// ---------------------------------------------------------------------------
// Kernel 2: PERSISTENT 256x256 MFMA GEMM + fused masked exp-sum.
// m201-faithful schedule: balanced 4-phase body (bar -> lgkm0 -> 16 MFMA ->
// bar) AND the deep staging ledger: tile s stages tile s+2's B and A-h0
// (A[p]h0/B[p] are WAR-free right after their P1/P2 reads drain), single
// counted VMC(6) per K-tile leaving 3 half-tiles in flight.
// Minimum issue-to-gate lead = 4 phases (R13 had 1 -> de-facto drain-0).
//
// Per K-tile s (p=s&1; quadrants 00,01,11,10; 16 MFMA each):
//  P1: ds a0(8),b0(4); stage A(s+1)h1->A[p^1]; lgkm(8); BAR; lgkm0; MM00; BAR
//  P2: ds b1(4);       stage A(s+2)h0->A[p];            BAR; lgkm0; MM01; BAR
//  P3: ds a1(8);       stage B(s+2)h0->B[p];            BAR; lgkm0; MM11; BAR
//  P4: (no ds);        stage B(s+2)h1->B[p];            BAR;
//      MM10; VMC(6); BAR
// vmcnt ledger at VMC(6)@P4(s) (2 loads per stage, issue order P1..P4):
//  outstanding >= [A(s+1)h1@P1][A(s+2)h0@P2][B(s+2)h0@P3][B(s+2)h1@P4] = 8
//  -> drains A(s+1)h1 and older (incl. A(s+1)h0@P2(s-1), B(s+1)@P3/P4(s-1)),
//  leaves tile s+2's 3 halves.  So ALL of tile s+1's operands are resident
//  before its P1, with every stage >= 4 phases old at its gate.
// WAR: A[p^1]h1 stage@P1(s): last read a1@P3(s-1), drained by its lgkm0, 2
//  barriers before.  A[p]h0 stage@P2(s): read a0@P1(s), drained P1 lgkm0 <
//  BAR(P1-end).  B[p]h0 stage@P3(s): read b0@P1(s).  B[p]h1 stage@P4(s):
//  read b1@P2(s).  Epilogue vmem is older than following stages; later
//  VMC(6) over-drains it (safe).
// ---------------------------------------------------------------------------
__global__ __launch_bounds__(512, 1) void sim_loss_kernel(
    const unsigned short* __restrict__ An, const unsigned short* __restrict__ Bn,
    const float* __restrict__ pos, float* __restrict__ S)
{
    __shared__ char lds[131072];   // A[2]: 0,32768 ; B[2]: 65536, 98304

    int tid  = threadIdx.x;
    int lane = tid & 63;
    int wave = tid >> 6;
    int wm = wave >> 2, wn = wave & 3;   // 2x4 wave grid, 128x64 per wave
    int fr = lane & 15;
    int q  = lane >> 4;

    int bid = blockIdx.x;   // 0..255

#define BASES(g, rB, cB) do {                                                        \
    int xcd_ = bid & 7, jj_ = bid >> 3;                                              \
    int qr_ = (g) >> 1, qc_ = ((g) & 1) ^ (qr_ & 1);                                 \
    (rB) = (qr_ * 16 + (xcd_ >> 1) * 4 + (jj_ >> 3)) * BM;                           \
    (cB) = (qc_ * 16 + (xcd_ & 1) * 8 + (jj_ & 7)) * BN;                             \
} while (0)

    f32x4 acc[8][4] = {};
    bf16x8 a[4][2];      // current mh half: 4 m-frags x 2 k-slices
    bf16x8 b0[2][2];     // nh0 fragments (read P1, used P1/P4)
    bf16x8 b1[2][2];     // nh1 fragments (read P2, used P2/P3)

    // ds_read addressing (read-side swizzle)
    int sw = (fr & 7) << 4;
    int c0 = (q * 16) ^ sw;
    int c1 = (64 + q * 16) ^ sw;
    int aRow = (wm * 128 + fr) * 128;
    int bRow = (wn * 64 + fr) * 128;

    // staging addressing (source-side swizzle, linear LDS dest)
    int strow = tid >> 3;                                  // 0..63
    int scb   = ((tid & 7) * 16) ^ ((strow & 7) << 4);
    int ldst = tid * 16;

#define PANELS(rB, cB, pA, pB) do {                                                  \
    (pA) = (const char*)An + (size_t)((rB) + strow) * 2048 + scb;                    \
    (pB) = (const char*)Bn + (size_t)((cB) + strow) * 2048 + scb;                    \
} while (0)

#define STAGE(gbase, u, h, ldsdst) do {                                              \
    async_copy16((gbase) + (size_t)(h) * 262144 + (size_t)(u) * 128,                 \
                 (ldsdst) + (h) * 16384 + ldst);                                     \
    async_copy16((gbase) + (size_t)(h) * 262144 + 131072 + (size_t)(u) * 128,        \
                 (ldsdst) + (h) * 16384 + 8192 + ldst);                              \
} while (0)

#define LDA_(p, mh) do {                                                             \
    const char* _s = lds + (p) * 32768;                                              \
    _Pragma("unroll") for (int m = 0; m < 4; ++m) {                                  \
        a[m][0] = *(const bf16x8*)(_s + aRow + (mh) * 8192 + m * 2048 + c0);         \
        a[m][1] = *(const bf16x8*)(_s + aRow + (mh) * 8192 + m * 2048 + c1);         \
    }                                                                                \
} while (0)

#define LDB_(arr, p, nh) do {                                                        \
    const char* _s = lds + 65536 + (p) * 32768;                                      \
    _Pragma("unroll") for (int n = 0; n < 2; ++n) {                                  \
        arr[n][0] = *(const bf16x8*)(_s + bRow + (nh) * 4096 + n * 2048 + c0);       \
        arr[n][1] = *(const bf16x8*)(_s + bRow + (nh) * 4096 + n * 2048 + c1);       \
    }                                                                                \
} while (0)

#define MM_(barr, mo, no) do {                                                       \
    _Pragma("unroll") for (int m = 0; m < 4; ++m)                                    \
    _Pragma("unroll") for (int n = 0; n < 2; ++n) {                                  \
        acc[(mo)+m][(no)+n] = __builtin_amdgcn_mfma_f32_16x16x32_bf16(               \
            a[m][0], barr[n][0], acc[(mo)+m][(no)+n], 0, 0, 0);                      \
        acc[(mo)+m][(no)+n] = __builtin_amdgcn_mfma_f32_16x16x32_bf16(               \
            a[m][1], barr[n][1], acc[(mo)+m][(no)+n], 0, 0, 0);                      \
    }                                                                                \
} while (0)

#define BAR() __builtin_amdgcn_s_barrier()
#define SCH() __builtin_amdgcn_sched_barrier(0)
#define LGKM(n) asm volatile("s_waitcnt lgkmcnt(" #n ")" ::: "memory")
#define VMC(n)  asm volatile("s_waitcnt vmcnt(" #n ")" ::: "memory")
#define PRI1() __builtin_amdgcn_s_setprio(1)
#define PRI0() __builtin_amdgcn_s_setprio(0)

// gA1/uA1: A(s+1) (h1 staged); gA2/uA2: A(s+2) (h0); gB2/uB2: B(s+2) (h0,h1)
#define KTILE(p, gA1, uA1, gA2, uA2, gB2, uB2) do {                                  \
    char* stA1 = lds + ((p) ^ 1) * 32768;                                            \
    char* stA2 = lds + (p) * 32768;                                                  \
    char* stB2 = lds + 65536 + (p) * 32768;                                          \
    /* P1: quad (mh0,nh0) */                                                         \
    LDA_((p), 0); LDB_(b0, (p), 0); STAGE((gA1), (uA1), 1, stA1);                    \
    LGKM(8); BAR(); SCH();                                                           \
    LGKM(0); PRI1(); MM_(b0, 0, 0); PRI0(); BAR(); SCH();                            \
    /* P2: quad (mh0,nh1) */                                                         \
    LDB_(b1, (p), 1); STAGE((gA2), (uA2), 0, stA2);                                  \
    BAR(); SCH();                                                                    \
    LGKM(0); PRI1(); MM_(b1, 0, 2); PRI0(); BAR(); SCH();                            \
    /* P3: quad (mh1,nh1) */                                                         \
    LDA_((p), 1); STAGE((gB2), (uB2), 0, stB2);                                      \
    BAR(); SCH();                                                                    \
    LGKM(0); PRI1(); MM_(b1, 4, 2); PRI0(); BAR(); SCH();                            \
    /* P4: quad (mh1,nh0) */                                                         \
    STAGE((gB2), (uB2), 1, stB2);                                                    \
    BAR(); SCH();                                                                    \
    PRI1(); MM_(b0, 4, 0); PRI0(); VMC(6); BAR(); SCH();                             \
} while (0)

    int rowB, colB;
    BASES(0, rowB, colB);
    const char *gAc, *gBc;
    PANELS(rowB, colB, gAc, gBc);

    // Prologue: A(0) full -> A[0]; B(0) full -> B[0]; A(1)h0 -> A[1];
    // B(1)h0,h1 -> B[1].  Issue order matters: VMC(6) drains A(0)+B(0)
    // (8 loads), leaves {A(1)h0, B(1)h0, B(1)h1} in flight (steady-state
    // image of the P2/P3/P4 stages of a virtual tile -1).
    STAGE(gAc, 0, 0, lds);
    STAGE(gAc, 0, 1, lds);
    STAGE(gBc, 0, 0, lds + 65536);
    STAGE(gBc, 0, 1, lds + 65536);
    STAGE(gAc, 1, 0, lds + 32768);
    STAGE(gBc, 1, 0, lds + 98304);
    STAGE(gBc, 1, 1, lds + 98304);
    VMC(6);
    BAR();
    SCH();

    #pragma unroll 1
    for (int g = 0; g < 4; ++g) {
        int gn = (g < 3) ? g + 1 : 3;
        int rowBn, colBn;
        BASES(gn, rowBn, colBn);
        const char *gAn2, *gBn2;
        PANELS(rowBn, colBn, gAn2, gBn2);

        // tiles 0..13: all staging refs (s+1 <= 14, s+2 <= 15) stay in-gen.
        #pragma unroll 1
        for (int tt = 0; tt < 7; ++tt) {
            int t0 = 2 * tt;
            KTILE(0, gAc, t0 + 1, gAc, t0 + 2, gBc, t0 + 2);
            KTILE(1, gAc, t0 + 2, gAc, t0 + 3, gBc, t0 + 3);
        }
        // tile 14: A(15)h1 in-gen; A(16)h0, B(16) -> next gen slot 0.
        KTILE(0, gAc, 15, gAn2, 0, gBn2, 0);
        // tile 15: A(16)h1 -> next slot 0; A(17)h0, B(17) -> next slot 1.
        KTILE(1, gAn2, 0, gAn2, 1, gBn2, 1);

        // Epilogue for tile g (next gen's tile-0 operands fully drained at
        // P4(15)'s VMC(6); tile-1 operands still in flight).
        #pragma unroll
        for (int m = 0; m < 8; ++m) {
            #pragma unroll
            for (int j2 = 0; j2 < 4; ++j2) {
                int i = rowB + wm * 128 + m * 16 + q * 4 + j2;
                float p  = pos[i];
                float up = TOPM * p, lo = BOTM * p;
                float rs = 0.0f;
                #pragma unroll
                for (int n = 0; n < 4; ++n) {
                    float sv = acc[m][n][j2];
                    int col = colB + wn * 64 + n * 16 + fr;
                    if (sv <= up && sv >= lo && col != i)
                        rs += __expf((sv - p) * INV_TAU);
                }
                #pragma unroll
                for (int d = 1; d < 16; d <<= 1)
                    rs += __shfl_xor(rs, d);
                if (fr == 0 && rs != 0.0f)
                    atomicAdd(&S[i], rs);
            }
        }
        #pragma unroll
        for (int m2 = 0; m2 < 8; ++m2)
            #pragma unroll
            for (int n2 = 0; n2 < 4; ++n2)
                acc[m2][n2] = (f32x4){0.0f, 0.0f, 0.0f, 0.0f};

        gAc = gAn2; gBc = gBn2; rowB = rowBn; colB = colBn;
    }
    LGKM(0);
    VMC(0);    // drain redundant g=3 restages + atomics before endpgm

#undef BASES
#undef PANELS
#undef STAGE
#undef LDA_
#undef LDB_
#undef MM_
#undef BAR
#undef SCH
#undef LGKM
#undef VMC
#undef PRI1
#undef PRI0
#undef KTILE
}

// ---------------------------------------------------------------------------
// Kernel 3: per_row = log1p(S_i) for rows with any negative; mean over valid.
// ---------------------------------------------------------------------------
__global__ __launch_bounds__(256) void finalize_kernel(
    const float* __restrict__ S, float* __restrict__ out)
{
    int t = threadIdx.x;
    float tot = 0.0f;
    int c = 0;
    for (int i = t; i < BATCH; i += 256) {
        float s = S[i];
        if (s > 0.0f) { tot += log1pf(s); c += 1; }
    }
    #pragma unroll
    for (int d = 32; d > 0; d >>= 1) {
        tot += __shfl_down(tot, d);
        c   += __shfl_down(c, d);
    }
    __shared__ float st[4];
    __shared__ int   sc[4];
    int lane = t & 63, w = t >> 6;
    if (lane == 0) { st[w] = tot; sc[w] = c; }
    __syncthreads();
    if (t == 0) {
        float T = st[0] + st[1] + st[2] + st[3];
        int   C = sc[0] + sc[1] + sc[2] + sc[3];
        out[0] = T / (float)(C > 0 ? C : 1);
    }
}

extern "C" void kernel_launch(void* const* d_in, const int* in_sizes, int n_in,
                              void* d_out, int out_size, void* d_ws, size_t ws_size,
                              hipStream_t stream) {
    const float* A = (const float*)d_in[0];
    const float* B = (const float*)d_in[1];

    char* ws = (char*)d_ws;
    unsigned short* An = (unsigned short*)ws;
    unsigned short* Bn = An + (size_t)BATCH * DIM;
    float* pos = (float*)(Bn + (size_t)BATCH * DIM);
    float* S   = pos + BATCH;
    float* out = (float*)d_out;

    prep_kernel<<<BATCH, 256, 0, stream>>>(A, B, An, Bn, pos, S);
    sim_loss_kernel<<<256, 512, 0, stream>>>(An, Bn, pos, S);
    finalize_kernel<<<1, 256, 0, stream>>>(S, out);
}

// Round 15
// 214.275 us; speedup vs baseline: 1.5760x; 1.0336x over previous
//
#include <hip/hip_runtime.h>
#include <hip/hip_bf16.h>

#define BATCH 8192
#define DIM   1024
#define INV_TAU (1.0f / 0.07f)
#define TOPM 0.95f
#define BOTM 0.05f

#define BM 256
#define BN 256
#define BK 64
#define NT (DIM / BK)   // 16 K-tiles per output tile

typedef __attribute__((ext_vector_type(4))) float f32x4;
typedef __attribute__((ext_vector_type(8))) short bf16x8;

typedef __attribute__((address_space(3))) void       lds_void_t;
typedef const __attribute__((address_space(1))) void gbl_void_t;

__device__ inline void async_copy16(const void* g, void* l) {
    __builtin_amdgcn_global_load_lds((gbl_void_t*)g, (lds_void_t*)l, 16, 0, 0);
}

__device__ inline unsigned short f2bf(float f) {
    __hip_bfloat16 h = __float2bfloat16(f);
    return *reinterpret_cast<unsigned short*>(&h);
}

// ---------------------------------------------------------------------------
// Kernel 1: per-row L2 norms, exact fp32 pos, bf16 writes, zero-init S.
// ---------------------------------------------------------------------------
__global__ __launch_bounds__(256) void prep_kernel(
    const float* __restrict__ A, const float* __restrict__ B,
    unsigned short* __restrict__ An, unsigned short* __restrict__ Bn,
    float* __restrict__ pos, float* __restrict__ S)
{
    int row = blockIdx.x;
    int t = threadIdx.x;
    const float4* a4 = (const float4*)(A + (size_t)row * DIM);
    const float4* b4 = (const float4*)(B + (size_t)row * DIM);
    float4 av = a4[t];
    float4 bv = b4[t];
    float sa = av.x*av.x + av.y*av.y + av.z*av.z + av.w*av.w;
    float sb = bv.x*bv.x + bv.y*bv.y + bv.z*bv.z + bv.w*bv.w;
    float dp = av.x*bv.x + av.y*bv.y + av.z*bv.z + av.w*bv.w;
    #pragma unroll
    for (int d = 32; d > 0; d >>= 1) {
        sa += __shfl_down(sa, d);
        sb += __shfl_down(sb, d);
        dp += __shfl_down(dp, d);
    }
    __shared__ float red[3][4];
    int lane = t & 63, w = t >> 6;
    if (lane == 0) { red[0][w] = sa; red[1][w] = sb; red[2][w] = dp; }
    __syncthreads();
    sa = red[0][0] + red[0][1] + red[0][2] + red[0][3];
    sb = red[1][0] + red[1][1] + red[1][2] + red[1][3];
    dp = red[2][0] + red[2][1] + red[2][2] + red[2][3];
    float ra = rsqrtf(sa);
    float rb = rsqrtf(sb);
    if (t == 0) {
        pos[row] = dp * ra * rb;
        S[row] = 0.0f;
    }
    ushort4 oa, ob;
    oa.x = f2bf(av.x * ra); oa.y = f2bf(av.y * ra);
    oa.z = f2bf(av.z * ra); oa.w = f2bf(av.w * ra);
    ob.x = f2bf(bv.x * rb); ob.y = f2bf(bv.y * rb);
    ob.z = f2bf(bv.z * rb); ob.w = f2bf(bv.w * rb);
    ((ushort4*)(An + (size_t)row * DIM))[t] = oa;
    ((ushort4*)(Bn + (size_t)row * DIM))[t] = ob;
}

// ---------------------------------------------------------------------------
// Kernel 2: PERSISTENT 256x256 MFMA GEMM + fused masked exp-sum.
// COMPILER-SCHEDULED single-barrier K-tile (pure m97 pattern, scaled up):
// zero inline-asm waits, zero sched_barriers; per K-tile t (p=t&1):
//   issue 8 stage-loads for tile t+1 -> A[p^1],B[p^1]   (global_load_lds)
//   24 C++ ds_reads of A[p],B[p] -> frags               (compiler lgkm)
//   64 MFMA (setprio-wrapped)                            (compiler-gated)
//   __syncthreads()   (emits vmcnt(0)+lgkmcnt(0) drain + s_barrier)
// Correctness: stages of t+1 only touch [p^1], whose readers (tile t-1, all
// waves) retired before the t-1 -> t barrier.  Reads of [p] in tile t are
// gated by the vmcnt(0) inside t-1's __syncthreads, draining stage loads
// issued at the START of tile t-1 (~full-tile issue-to-gate lead, so the
// drain waits on ~2000-cycle-old loads).  One barrier per K-tile total.
// Epilogue atomics are drained by the next KTILE's syncthreads (harmless).
// ---------------------------------------------------------------------------
__global__ __launch_bounds__(512, 1) void sim_loss_kernel(
    const unsigned short* __restrict__ An, const unsigned short* __restrict__ Bn,
    const float* __restrict__ pos, float* __restrict__ S)
{
    __shared__ char lds[131072];   // A[2]: 0,32768 ; B[2]: 65536, 98304

    int tid  = threadIdx.x;
    int lane = tid & 63;
    int wave = tid >> 6;
    int wm = wave >> 2, wn = wave & 3;   // 2x4 wave grid, 128x64 per wave
    int fr = lane & 15;
    int q  = lane >> 4;

    int bid = blockIdx.x;   // 0..255

#define BASES(g, rB, cB) do {                                                        \
    int xcd_ = bid & 7, jj_ = bid >> 3;                                              \
    int qr_ = (g) >> 1, qc_ = ((g) & 1) ^ (qr_ & 1);                                 \
    (rB) = (qr_ * 16 + (xcd_ >> 1) * 4 + (jj_ >> 3)) * BM;                           \
    (cB) = (qc_ * 16 + (xcd_ & 1) * 8 + (jj_ & 7)) * BN;                             \
} while (0)

    f32x4 acc[8][4] = {};
    bf16x8 a0[4][2];     // mh0 fragments
    bf16x8 a1[4][2];     // mh1 fragments
    bf16x8 b0[2][2];     // nh0 fragments
    bf16x8 b1[2][2];     // nh1 fragments

    // ds_read addressing (read-side swizzle)
    int sw = (fr & 7) << 4;
    int c0 = (q * 16) ^ sw;
    int c1 = (64 + q * 16) ^ sw;
    int aRow = (wm * 128 + fr) * 128;
    int bRow = (wn * 64 + fr) * 128;

    // staging addressing (source-side swizzle, linear LDS dest)
    int strow = tid >> 3;                                  // 0..63
    int scb   = ((tid & 7) * 16) ^ ((strow & 7) << 4);
    int ldst = tid * 16;

#define PANELS(rB, cB, pA, pB) do {                                                  \
    (pA) = (const char*)An + (size_t)((rB) + strow) * 2048 + scb;                    \
    (pB) = (const char*)Bn + (size_t)((cB) + strow) * 2048 + scb;                    \
} while (0)

#define STAGE(gbase, u, h, ldsdst) do {                                              \
    async_copy16((gbase) + (size_t)(h) * 262144 + (size_t)(u) * 128,                 \
                 (ldsdst) + (h) * 16384 + ldst);                                     \
    async_copy16((gbase) + (size_t)(h) * 262144 + 131072 + (size_t)(u) * 128,        \
                 (ldsdst) + (h) * 16384 + 8192 + ldst);                              \
} while (0)

#define LDA_(arr, p, mh) do {                                                        \
    const char* _s = lds + (p) * 32768;                                              \
    _Pragma("unroll") for (int m = 0; m < 4; ++m) {                                  \
        arr[m][0] = *(const bf16x8*)(_s + aRow + (mh) * 8192 + m * 2048 + c0);       \
        arr[m][1] = *(const bf16x8*)(_s + aRow + (mh) * 8192 + m * 2048 + c1);       \
    }                                                                                \
} while (0)

#define LDB_(arr, p, nh) do {                                                        \
    const char* _s = lds + 65536 + (p) * 32768;                                      \
    _Pragma("unroll") for (int n = 0; n < 2; ++n) {                                  \
        arr[n][0] = *(const bf16x8*)(_s + bRow + (nh) * 4096 + n * 2048 + c0);       \
        arr[n][1] = *(const bf16x8*)(_s + bRow + (nh) * 4096 + n * 2048 + c1);       \
    }                                                                                \
} while (0)

#define MMA_(aarr, barr, mo, no) do {                                                \
    _Pragma("unroll") for (int m = 0; m < 4; ++m)                                    \
    _Pragma("unroll") for (int n = 0; n < 2; ++n) {                                  \
        acc[(mo)+m][(no)+n] = __builtin_amdgcn_mfma_f32_16x16x32_bf16(               \
            aarr[m][0], barr[n][0], acc[(mo)+m][(no)+n], 0, 0, 0);                   \
        acc[(mo)+m][(no)+n] = __builtin_amdgcn_mfma_f32_16x16x32_bf16(               \
            aarr[m][1], barr[n][1], acc[(mo)+m][(no)+n], 0, 0, 0);                   \
    }                                                                                \
} while (0)

#define PRI1() __builtin_amdgcn_s_setprio(1)
#define PRI0() __builtin_amdgcn_s_setprio(0)

// Stage tile t+1 into [p^1]; read [p]; compute; one barrier.
#define KTILE(p, pA_, uA, pB_, uB) do {                                              \
    char* stA = lds + ((p) ^ 1) * 32768;                                             \
    char* stB = lds + 65536 + ((p) ^ 1) * 32768;                                     \
    STAGE((pA_), (uA), 0, stA); STAGE((pA_), (uA), 1, stA);                          \
    STAGE((pB_), (uB), 0, stB); STAGE((pB_), (uB), 1, stB);                          \
    LDA_(a0, (p), 0); LDA_(a1, (p), 1); LDB_(b0, (p), 0); LDB_(b1, (p), 1);          \
    PRI1();                                                                          \
    MMA_(a0, b0, 0, 0); MMA_(a0, b1, 0, 2); MMA_(a1, b1, 4, 2); MMA_(a1, b0, 4, 0);  \
    PRI0();                                                                          \
    __syncthreads();                                                                 \
} while (0)

    int rowB, colB;
    BASES(0, rowB, colB);
    const char *gAc, *gBc;
    PANELS(rowB, colB, gAc, gBc);

    // Prologue: A(0)->A[0], B(0)->B[0]; syncthreads drains (vmcnt 0) + bar.
    STAGE(gAc, 0, 0, lds);
    STAGE(gAc, 0, 1, lds);
    STAGE(gBc, 0, 0, lds + 65536);
    STAGE(gBc, 0, 1, lds + 65536);
    __syncthreads();

    #pragma unroll 1
    for (int g = 0; g < 4; ++g) {
        int gn = (g < 3) ? g + 1 : 3;
        int rowBn, colBn;
        BASES(gn, rowBn, colBn);
        const char *gAn2, *gBn2;
        PANELS(rowBn, colBn, gAn2, gBn2);

        // t = 0..13: stage u = t+1 (in-gen).
        #pragma unroll 1
        for (int tt = 0; tt < 7; ++tt) {
            KTILE(0, gAc, 2 * tt + 1, gBc, 2 * tt + 1);
            KTILE(1, gAc, 2 * tt + 2, gBc, 2 * tt + 2);
        }
        // t=14: stage u=15 (in-gen).  t=15: stage next gen's tile 0 -> [0].
        KTILE(0, gAc, 15, gBc, 15);
        KTILE(1, gAn2, 0, gBn2, 0);

        // Epilogue for tile g (next gen's tile-0 data already resident).
        #pragma unroll
        for (int m = 0; m < 8; ++m) {
            #pragma unroll
            for (int j2 = 0; j2 < 4; ++j2) {
                int i = rowB + wm * 128 + m * 16 + q * 4 + j2;
                float p  = pos[i];
                float up = TOPM * p, lo = BOTM * p;
                float rs = 0.0f;
                #pragma unroll
                for (int n = 0; n < 4; ++n) {
                    float sv = acc[m][n][j2];
                    int col = colB + wn * 64 + n * 16 + fr;
                    if (sv <= up && sv >= lo && col != i)
                        rs += __expf((sv - p) * INV_TAU);
                }
                #pragma unroll
                for (int d = 1; d < 16; d <<= 1)
                    rs += __shfl_xor(rs, d);
                if (fr == 0 && rs != 0.0f)
                    atomicAdd(&S[i], rs);
            }
        }
        #pragma unroll
        for (int m2 = 0; m2 < 8; ++m2)
            #pragma unroll
            for (int n2 = 0; n2 < 4; ++n2)
                acc[m2][n2] = (f32x4){0.0f, 0.0f, 0.0f, 0.0f};

        gAc = gAn2; gBc = gBn2; rowB = rowBn; colB = colBn;
    }

#undef BASES
#undef PANELS
#undef STAGE
#undef LDA_
#undef LDB_
#undef MMA_
#undef PRI1
#undef PRI0
#undef KTILE
}

// ---------------------------------------------------------------------------
// Kernel 3: per_row = log1p(S_i) for rows with any negative; mean over valid.
// ---------------------------------------------------------------------------
__global__ __launch_bounds__(256) void finalize_kernel(
    const float* __restrict__ S, float* __restrict__ out)
{
    int t = threadIdx.x;
    float tot = 0.0f;
    int c = 0;
    for (int i = t; i < BATCH; i += 256) {
        float s = S[i];
        if (s > 0.0f) { tot += log1pf(s); c += 1; }
    }
    #pragma unroll
    for (int d = 32; d > 0; d >>= 1) {
        tot += __shfl_down(tot, d);
        c   += __shfl_down(c, d);
    }
    __shared__ float st[4];
    __shared__ int   sc[4];
    int lane = t & 63, w = t >> 6;
    if (lane == 0) { st[w] = tot; sc[w] = c; }
    __syncthreads();
    if (t == 0) {
        float T = st[0] + st[1] + st[2] + st[3];
        int   C = sc[0] + sc[1] + sc[2] + sc[3];
        out[0] = T / (float)(C > 0 ? C : 1);
    }
}

extern "C" void kernel_launch(void* const* d_in, const int* in_sizes, int n_in,
                              void* d_out, int out_size, void* d_ws, size_t ws_size,
                              hipStream_t stream) {
    const float* A = (const float*)d_in[0];
    const float* B = (const float*)d_in[1];

    char* ws = (char*)d_ws;
    unsigned short* An = (unsigned short*)ws;
    unsigned short* Bn = An + (size_t)BATCH * DIM;
    float* pos = (float*)(Bn + (size_t)BATCH * DIM);
    float* S   = pos + BATCH;
    float* out = (float*)d_out;

    prep_kernel<<<BATCH, 256, 0, stream>>>(A, B, An, Bn, pos, S);
    sim_loss_kernel<<<256, 512, 0, stream>>>(An, Bn, pos, S);
    finalize_kernel<<<1, 256, 0, stream>>>(S, out);
}